// Round 9
// baseline (109.736 us; speedup 1.0000x reference)
//
#include <hip/hip_runtime.h>

#define HH 256
#define WW 256
#define ZZ 256
#define BBH 512                           // B*H lines
#define LSTRIDE (WW * ZZ)                 // floats between h-lines
#define NROWS (BBH * WW)                  // 131072
#define NELEM ((long long)NROWS * ZZ)     // 33554432

#define SEGW 8
#define NTW (WW / SEGW)                   // 32 w-tiles
#define NPAIR (BBH / 2)                   // 256 line pairs
#define NSEG (NPAIR * NTW)                // 8192 wave tasks
#define WPB 4
#define NBLK (NSEG / WPB)                 // 2048 blocks

typedef float vf4 __attribute__((ext_vector_type(4)));

__device__ __forceinline__ vf4 ld4(const float* p) { return *(const vf4*)p; }
__device__ __forceinline__ vf4 ldnt4(const float* p) {
    return __builtin_nontemporal_load((const vf4*)p);
}

// aligned store of one output row at d_out+1: lane j stores slot j+1 =
// {own o.w, next-lane o.x,o.y,o.z}; edges scalar. rowp = outD + r*ZZ.
__device__ __forceinline__ void store_row(float* rowp, vf4 o, int lane) {
    const float nx = __shfl_down(o.x, 1);
    const float ny = __shfl_down(o.y, 1);
    const float nz = __shfl_down(o.z, 1);
    if (lane < 63) {
        vf4 st = {o.w, nx, ny, nz};
        __builtin_nontemporal_store(st, (vf4*)(rowp + 4 * (lane + 1)));
    }
    if (lane == 0) {
        __builtin_nontemporal_store(o.x, rowp + 1);
        __builtin_nontemporal_store(o.y, rowp + 2);
        __builtin_nontemporal_store(o.z, rowp + 3);
    }
    if (lane == 63) __builtin_nontemporal_store(o.w, rowp + ZZ);
}

// d_ws layout: float part_sum[NBLK]; float part_max[NBLK]
__global__ __launch_bounds__(256, 4) void stencil7_kernel(
    const float* __restrict__ x, const float* __restrict__ coeff,
    const float* __restrict__ ref, float* __restrict__ outD,
    float* __restrict__ part_sum, float* __restrict__ part_max)
{
    const int tid  = threadIdx.x;
    const int k    = tid >> 6;
    const int lane = tid & 63;
    const int seg  = __builtin_amdgcn_readfirstlane(blockIdx.x * WPB + k);
    const int p    = seg >> 5;            // line-pair id
    const int wt   = seg & (NTW - 1);     // w-tile id
    const int bh0  = p * 2;               // even line
    const int w0   = wt * SEGW;
    const int h0   = bh0 & (HH - 1);
    const bool hasS = (h0 > 0);           // row0 south exists
    const bool hasN = (h0 != HH - 2);     // row1 north exists (h1 != 255)
    const long long SOFF = hasS ? -(long long)LSTRIDE : 0;
    const long long NOFF = hasN ? 2LL * LSTRIDE : (long long)LSTRIDE;
    const int lo = lane << 2;

    const float* px0  = x   + (long long)(bh0 * WW + w0) * ZZ + lo;
    const float* px1  = px0 + LSTRIDE;
    const float* prf0 = ref + (long long)(bh0 * WW + w0) * ZZ + lo;
    const float* prf1 = prf0 + LSTRIDE;
    const float* pc0  = coeff + 7LL * (bh0 * WW + w0);
    const float* pc1  = pc0 + 7 * WW;
    float* prow0 = outD + (long long)(bh0 * WW + w0) * ZZ;
    float* prow1 = prow0 + LSTRIDE;

    const vf4 z4 = {0.f, 0.f, 0.f, 0.f};

    // ---- prologue ----
    vf4 cw0, cw1;
    if (w0 > 0) { cw0 = ld4(px0 - ZZ); cw1 = ld4(px1 - ZZ); }
    else        { cw0 = z4;            cw1 = z4; }
    vf4 c00 = ld4(px0);           vf4 c10 = ld4(px1);
    vf4 c01 = ld4(px0 + ZZ);      vf4 c11 = ld4(px1 + ZZ);
    vf4 sC  = ld4(px0 + SOFF);    vf4 nC  = ld4(px0 + NOFF);
    vf4 rf0 = ldnt4(prf0);        vf4 rf1 = ldnt4(prf1);
    float k0 = pc0[0], k1 = pc0[1], k2 = hasS ? pc0[2] : 0.f, k3 = pc0[3],
          k4 = pc0[4], k5 = pc0[5], k6 = pc0[6];
    float j0 = pc1[0], j1 = pc1[1], j2 = pc1[2], j3 = hasN ? pc1[3] : 0.f,
          j4 = pc1[4], j5 = pc1[5], j6 = pc1[6];

    float acc_s = 0.f, acc_m = 0.f;

    #pragma unroll
    for (int i = 0; i < SEGW - 1; ++i) {
        // ---- prefetch for step i+1 ----
        int ce = w0 + i + 2; if (ce > WW - 1) ce = WW - 1;   // column clamp
        const long long ceo = (long long)(ce - w0) * ZZ;
        vf4 c0n = ld4(px0 + ceo);
        vf4 c1n = ld4(px1 + ceo);
        const long long r1o = (long long)(i + 1) * ZZ;
        vf4 sN  = ld4(px0 + r1o + SOFF);
        vf4 nN  = ld4(px0 + r1o + NOFF);
        vf4 rf0n = ldnt4(prf0 + r1o);
        vf4 rf1n = ldnt4(prf1 + r1o);
        const float* qc0 = pc0 + 7 * (i + 1);
        const float* qc1 = pc1 + 7 * (i + 1);
        const float m0 = qc0[0], m1 = qc0[1], m2 = hasS ? qc0[2] : 0.f,
                    m3 = qc0[3], m4 = qc0[4], m5 = qc0[5], m6 = qc0[6];
        const float n0 = qc1[0], n1 = qc1[1], n2 = qc1[2],
                    n3 = hasN ? qc1[3] : 0.f, n4 = qc1[4], n5 = qc1[5], n6 = qc1[6];

        // ---- compute row0 (line bh0): S=sC, N=c10 ----
        {
            float bm1 = __shfl_up(c00.w, 1);
            if (lane == 0) bm1 = 0.f;
            float tp1 = __shfl_down(c00.x, 1);
            if (lane == 63) tp1 = 0.f;
            const vf4 bot = {bm1, c00.x, c00.y, c00.z};
            const vf4 top = {c00.y, c00.z, c00.w, tp1};
            const vf4 o = k0*cw0 + k1*c01 + k2*sC + k3*c10 + k4*bot + k5*top + k6*c00;
            store_row(prow0 + (long long)i * ZZ, o, lane);
            const vf4 e = o - rf0;
            acc_s += e.x*e.x + e.y*e.y + e.z*e.z + e.w*e.w;
            acc_m  = fmaxf(acc_m, fmaxf(fmaxf(fabsf(e.x), fabsf(e.y)),
                                        fmaxf(fabsf(e.z), fabsf(e.w))));
        }
        // ---- compute row1 (line bh0+1): S=c00, N=nC ----
        {
            float bm1 = __shfl_up(c10.w, 1);
            if (lane == 0) bm1 = 0.f;
            float tp1 = __shfl_down(c10.x, 1);
            if (lane == 63) tp1 = 0.f;
            const vf4 bot = {bm1, c10.x, c10.y, c10.z};
            const vf4 top = {c10.y, c10.z, c10.w, tp1};
            const vf4 o = j0*cw1 + j1*c11 + j2*c00 + j3*nC + j4*bot + j5*top + j6*c10;
            store_row(prow1 + (long long)i * ZZ, o, lane);
            const vf4 e = o - rf1;
            acc_s += e.x*e.x + e.y*e.y + e.z*e.z + e.w*e.w;
            acc_m  = fmaxf(acc_m, fmaxf(fmaxf(fabsf(e.x), fabsf(e.y)),
                                        fmaxf(fabsf(e.z), fabsf(e.w))));
        }

        // ---- rotate ----
        cw0 = c00; c00 = c01; c01 = c0n;
        cw1 = c10; c10 = c11; c11 = c1n;
        sC = sN; nC = nN; rf0 = rf0n; rf1 = rf1n;
        k0 = m0; k1 = m1; k2 = m2; k3 = m3; k4 = m4; k5 = m5; k6 = m6;
        j0 = n0; j1 = n1; j2 = n2; j3 = n3; j4 = n4; j5 = n5; j6 = n6;
    }

    // ---- peeled last step (i = SEGW-1): east may be global E boundary ----
    {
        const int i = SEGW - 1;
        if (w0 + i == WW - 1) { k1 = 0.f; j1 = 0.f; }   // zero east coeff
        {
            float bm1 = __shfl_up(c00.w, 1);
            if (lane == 0) bm1 = 0.f;
            float tp1 = __shfl_down(c00.x, 1);
            if (lane == 63) tp1 = 0.f;
            const vf4 bot = {bm1, c00.x, c00.y, c00.z};
            const vf4 top = {c00.y, c00.z, c00.w, tp1};
            const vf4 o = k0*cw0 + k1*c01 + k2*sC + k3*c10 + k4*bot + k5*top + k6*c00;
            store_row(prow0 + (long long)i * ZZ, o, lane);
            const vf4 e = o - rf0;
            acc_s += e.x*e.x + e.y*e.y + e.z*e.z + e.w*e.w;
            acc_m  = fmaxf(acc_m, fmaxf(fmaxf(fabsf(e.x), fabsf(e.y)),
                                        fmaxf(fabsf(e.z), fabsf(e.w))));
        }
        {
            float bm1 = __shfl_up(c10.w, 1);
            if (lane == 0) bm1 = 0.f;
            float tp1 = __shfl_down(c10.x, 1);
            if (lane == 63) tp1 = 0.f;
            const vf4 bot = {bm1, c10.x, c10.y, c10.z};
            const vf4 top = {c10.y, c10.z, c10.w, tp1};
            const vf4 o = j0*cw1 + j1*c11 + j2*c00 + j3*nC + j4*bot + j5*top + j6*c10;
            store_row(prow1 + (long long)i * ZZ, o, lane);
            const vf4 e = o - rf1;
            acc_s += e.x*e.x + e.y*e.y + e.z*e.z + e.w*e.w;
            acc_m  = fmaxf(acc_m, fmaxf(fmaxf(fabsf(e.x), fabsf(e.y)),
                                        fmaxf(fabsf(e.z), fabsf(e.w))));
        }
    }

    // ---- wave + block reduction ----
    #pragma unroll
    for (int off = 32; off > 0; off >>= 1) {
        acc_s += __shfl_down(acc_s, off);
        acc_m  = fmaxf(acc_m, __shfl_down(acc_m, off));
    }
    __shared__ float ss[WPB];
    __shared__ float sm[WPB];
    if (lane == 0) { ss[k] = acc_s; sm[k] = acc_m; }
    __syncthreads();
    if (tid == 0) {
        part_sum[blockIdx.x] = ss[0] + ss[1] + ss[2] + ss[3];
        part_max[blockIdx.x] = fmaxf(fmaxf(sm[0], sm[1]), fmaxf(sm[2], sm[3]));
    }
}

__global__ __launch_bounds__(256) void finalize_kernel(
    const float* __restrict__ part_sum, const float* __restrict__ part_max,
    float* __restrict__ loss_out, float* __restrict__ amax_out)
{
    const int tid  = threadIdx.x;
    const int wave = tid >> 6;
    const int lane = tid & 63;

    double s = 0.0;
    float  m = 0.f;
    for (int i = tid; i < NBLK; i += 256) {
        s += (double)part_sum[i];
        m  = fmaxf(m, part_max[i]);
    }
    #pragma unroll
    for (int off = 32; off > 0; off >>= 1) {
        s += __shfl_down(s, off);
        m  = fmaxf(m, __shfl_down(m, off));
    }
    __shared__ double ds[4];
    __shared__ float  dm[4];
    if (lane == 0) { ds[wave] = s; dm[wave] = m; }
    __syncthreads();
    if (tid == 0) {
        const double S = ds[0] + ds[1] + ds[2] + ds[3];
        const float  M = fmaxf(fmaxf(dm[0], dm[1]), fmaxf(dm[2], dm[3]));
        *loss_out = (float)(S / (double)NELEM);
        *amax_out = M;
    }
}

extern "C" void kernel_launch(void* const* d_in, const int* in_sizes, int n_in,
                              void* d_out, int out_size, void* d_ws, size_t ws_size,
                              hipStream_t stream) {
    const float* x     = (const float*)d_in[0];
    const float* coeff = (const float*)d_in[1];
    const float* ref   = (const float*)d_in[2];

    float* outf = (float*)d_out;
    float* loss_out = outf;               // d_out[0]
    float* amax_out = outf + 1 + NELEM;   // d_out[N+1]

    float* part_sum = (float*)d_ws;
    float* part_max = part_sum + NBLK;

    stencil7_kernel<<<dim3(NBLK), dim3(256), 0, stream>>>(
        x, coeff, ref, outf, part_sum, part_max);
    finalize_kernel<<<dim3(1), dim3(256), 0, stream>>>(
        part_sum, part_max, loss_out, amax_out);
}

// Round 10
// 74.488 us; speedup vs baseline: 1.4732x; 1.4732x over previous
//
#include <hip/hip_runtime.h>

#define HH 256
#define WW 256
#define ZZ 256
#define BBH 512                           // B*H lines
#define LSTRIDE (WW * ZZ)                 // floats between h-lines
#define NROWS (BBH * WW)                  // 131072
#define NELEM ((long long)NROWS * ZZ)     // 33554432

#define SEGW 8
#define NTW (WW / SEGW)                   // 32 w-tiles
#define NPAIR (BBH / 2)                   // 256 line pairs
#define NSEG (NPAIR * NTW)                // 8192 wave tasks
#define WPB 4
#define NBLK (NSEG / WPB)                 // 2048 blocks

typedef float vf4 __attribute__((ext_vector_type(4)));

__device__ __forceinline__ vf4 ld4(const float* p) { return *(const vf4*)p; }
__device__ __forceinline__ vf4 ldnt4(const float* p) {
    return __builtin_nontemporal_load((const vf4*)p);
}

// aligned store of one output row at d_out+1: lane j stores slot j+1 =
// {own o.w, next-lane o.x,o.y,o.z}; edges scalar. rowp = outD + r*ZZ.
__device__ __forceinline__ void store_row(float* rowp, vf4 o, int lane) {
    const float nx = __shfl_down(o.x, 1);
    const float ny = __shfl_down(o.y, 1);
    const float nz = __shfl_down(o.z, 1);
    if (lane < 63) {
        vf4 st = {o.w, nx, ny, nz};
        __builtin_nontemporal_store(st, (vf4*)(rowp + 4 * (lane + 1)));
    }
    if (lane == 0) {
        __builtin_nontemporal_store(o.x, rowp + 1);
        __builtin_nontemporal_store(o.y, rowp + 2);
        __builtin_nontemporal_store(o.z, rowp + 3);
    }
    if (lane == 63) __builtin_nontemporal_store(o.w, rowp + ZZ);
}

// d_ws layout: float part_sum[NBLK]; float part_max[NBLK]
__global__ __launch_bounds__(256) void stencil7_kernel(
    const float* __restrict__ x, const float* __restrict__ coeff,
    const float* __restrict__ ref, float* __restrict__ outD,
    float* __restrict__ part_sum, float* __restrict__ part_max)
{
    const int tid  = threadIdx.x;
    const int k    = tid >> 6;
    const int lane = tid & 63;
    const int seg  = __builtin_amdgcn_readfirstlane(blockIdx.x * WPB + k);
    const int p    = seg >> 5;            // line-pair id
    const int wt   = seg & (NTW - 1);     // w-tile id
    const int bh0  = p * 2;               // even line
    const int w0   = wt * SEGW;
    const int h0   = bh0 & (HH - 1);
    const bool hasS = (h0 > 0);           // row0 south exists
    const bool hasN = (h0 != HH - 2);     // row1 north exists (h1 != 255)
    const long long SOFF = hasS ? -(long long)LSTRIDE : 0;
    const long long NOFF = hasN ? 2LL * LSTRIDE : (long long)LSTRIDE;
    const int lo = lane << 2;

    const float* px0  = x   + (long long)(bh0 * WW + w0) * ZZ + lo;
    const float* px1  = px0 + LSTRIDE;
    const float* prf0 = ref + (long long)(bh0 * WW + w0) * ZZ + lo;
    const float* prf1 = prf0 + LSTRIDE;
    const float* pc0  = coeff + 7LL * (bh0 * WW + w0);
    const float* pc1  = pc0 + 7 * WW;
    float* prow0 = outD + (long long)(bh0 * WW + w0) * ZZ;
    float* prow1 = prow0 + LSTRIDE;

    const vf4 z4 = {0.f, 0.f, 0.f, 0.f};

    // ---- prologue ----
    vf4 cw0, cw1;
    if (w0 > 0) { cw0 = ld4(px0 - ZZ); cw1 = ld4(px1 - ZZ); }
    else        { cw0 = z4;            cw1 = z4; }
    vf4 c00 = ld4(px0);           vf4 c10 = ld4(px1);
    vf4 c01 = ld4(px0 + ZZ);      vf4 c11 = ld4(px1 + ZZ);
    vf4 sC  = ld4(px0 + SOFF);    vf4 nC  = ld4(px0 + NOFF);
    vf4 rf0 = ldnt4(prf0);        vf4 rf1 = ldnt4(prf1);
    float k0 = pc0[0], k1 = pc0[1], k2 = hasS ? pc0[2] : 0.f, k3 = pc0[3],
          k4 = pc0[4], k5 = pc0[5], k6 = pc0[6];
    float j0 = pc1[0], j1 = pc1[1], j2 = pc1[2], j3 = hasN ? pc1[3] : 0.f,
          j4 = pc1[4], j5 = pc1[5], j6 = pc1[6];

    float acc_s = 0.f, acc_m = 0.f;

    #pragma unroll
    for (int i = 0; i < SEGW - 1; ++i) {
        // ---- prefetch for step i+1 ----
        int ce = w0 + i + 2; if (ce > WW - 1) ce = WW - 1;   // column clamp
        const long long ceo = (long long)(ce - w0) * ZZ;
        vf4 c0n = ld4(px0 + ceo);
        vf4 c1n = ld4(px1 + ceo);
        const long long r1o = (long long)(i + 1) * ZZ;
        vf4 sN  = ld4(px0 + r1o + SOFF);
        vf4 nN  = ld4(px0 + r1o + NOFF);
        vf4 rf0n = ldnt4(prf0 + r1o);
        vf4 rf1n = ldnt4(prf1 + r1o);
        const float* qc0 = pc0 + 7 * (i + 1);
        const float* qc1 = pc1 + 7 * (i + 1);
        const float m0 = qc0[0], m1 = qc0[1], m2 = hasS ? qc0[2] : 0.f,
                    m3 = qc0[3], m4 = qc0[4], m5 = qc0[5], m6 = qc0[6];
        const float n0 = qc1[0], n1 = qc1[1], n2 = qc1[2],
                    n3 = hasN ? qc1[3] : 0.f, n4 = qc1[4], n5 = qc1[5], n6 = qc1[6];

        // ---- compute row0 (line bh0): S=sC, N=c10 ----
        {
            float bm1 = __shfl_up(c00.w, 1);
            if (lane == 0) bm1 = 0.f;
            float tp1 = __shfl_down(c00.x, 1);
            if (lane == 63) tp1 = 0.f;
            const vf4 bot = {bm1, c00.x, c00.y, c00.z};
            const vf4 top = {c00.y, c00.z, c00.w, tp1};
            const vf4 o = k0*cw0 + k1*c01 + k2*sC + k3*c10 + k4*bot + k5*top + k6*c00;
            store_row(prow0 + (long long)i * ZZ, o, lane);
            const vf4 e = o - rf0;
            acc_s += e.x*e.x + e.y*e.y + e.z*e.z + e.w*e.w;
            acc_m  = fmaxf(acc_m, fmaxf(fmaxf(fabsf(e.x), fabsf(e.y)),
                                        fmaxf(fabsf(e.z), fabsf(e.w))));
        }
        // ---- compute row1 (line bh0+1): S=c00, N=nC ----
        {
            float bm1 = __shfl_up(c10.w, 1);
            if (lane == 0) bm1 = 0.f;
            float tp1 = __shfl_down(c10.x, 1);
            if (lane == 63) tp1 = 0.f;
            const vf4 bot = {bm1, c10.x, c10.y, c10.z};
            const vf4 top = {c10.y, c10.z, c10.w, tp1};
            const vf4 o = j0*cw1 + j1*c11 + j2*c00 + j3*nC + j4*bot + j5*top + j6*c10;
            store_row(prow1 + (long long)i * ZZ, o, lane);
            const vf4 e = o - rf1;
            acc_s += e.x*e.x + e.y*e.y + e.z*e.z + e.w*e.w;
            acc_m  = fmaxf(acc_m, fmaxf(fmaxf(fabsf(e.x), fabsf(e.y)),
                                        fmaxf(fabsf(e.z), fabsf(e.w))));
        }

        // ---- rotate ----
        cw0 = c00; c00 = c01; c01 = c0n;
        cw1 = c10; c10 = c11; c11 = c1n;
        sC = sN; nC = nN; rf0 = rf0n; rf1 = rf1n;
        k0 = m0; k1 = m1; k2 = m2; k3 = m3; k4 = m4; k5 = m5; k6 = m6;
        j0 = n0; j1 = n1; j2 = n2; j3 = n3; j4 = n4; j5 = n5; j6 = n6;
    }

    // ---- peeled last step (i = SEGW-1): east may be global E boundary ----
    {
        const int i = SEGW - 1;
        if (w0 + i == WW - 1) { k1 = 0.f; j1 = 0.f; }   // zero east coeff
        {
            float bm1 = __shfl_up(c00.w, 1);
            if (lane == 0) bm1 = 0.f;
            float tp1 = __shfl_down(c00.x, 1);
            if (lane == 63) tp1 = 0.f;
            const vf4 bot = {bm1, c00.x, c00.y, c00.z};
            const vf4 top = {c00.y, c00.z, c00.w, tp1};
            const vf4 o = k0*cw0 + k1*c01 + k2*sC + k3*c10 + k4*bot + k5*top + k6*c00;
            store_row(prow0 + (long long)i * ZZ, o, lane);
            const vf4 e = o - rf0;
            acc_s += e.x*e.x + e.y*e.y + e.z*e.z + e.w*e.w;
            acc_m  = fmaxf(acc_m, fmaxf(fmaxf(fabsf(e.x), fabsf(e.y)),
                                        fmaxf(fabsf(e.z), fabsf(e.w))));
        }
        {
            float bm1 = __shfl_up(c10.w, 1);
            if (lane == 0) bm1 = 0.f;
            float tp1 = __shfl_down(c10.x, 1);
            if (lane == 63) tp1 = 0.f;
            const vf4 bot = {bm1, c10.x, c10.y, c10.z};
            const vf4 top = {c10.y, c10.z, c10.w, tp1};
            const vf4 o = j0*cw1 + j1*c11 + j2*c00 + j3*nC + j4*bot + j5*top + j6*c10;
            store_row(prow1 + (long long)i * ZZ, o, lane);
            const vf4 e = o - rf1;
            acc_s += e.x*e.x + e.y*e.y + e.z*e.z + e.w*e.w;
            acc_m  = fmaxf(acc_m, fmaxf(fmaxf(fabsf(e.x), fabsf(e.y)),
                                        fmaxf(fabsf(e.z), fabsf(e.w))));
        }
    }

    // ---- wave + block reduction ----
    #pragma unroll
    for (int off = 32; off > 0; off >>= 1) {
        acc_s += __shfl_down(acc_s, off);
        acc_m  = fmaxf(acc_m, __shfl_down(acc_m, off));
    }
    __shared__ float ss[WPB];
    __shared__ float sm[WPB];
    if (lane == 0) { ss[k] = acc_s; sm[k] = acc_m; }
    __syncthreads();
    if (tid == 0) {
        part_sum[blockIdx.x] = ss[0] + ss[1] + ss[2] + ss[3];
        part_max[blockIdx.x] = fmaxf(fmaxf(sm[0], sm[1]), fmaxf(sm[2], sm[3]));
    }
}

__global__ __launch_bounds__(256) void finalize_kernel(
    const float* __restrict__ part_sum, const float* __restrict__ part_max,
    float* __restrict__ loss_out, float* __restrict__ amax_out)
{
    const int tid  = threadIdx.x;
    const int wave = tid >> 6;
    const int lane = tid & 63;

    double s = 0.0;
    float  m = 0.f;
    for (int i = tid; i < NBLK; i += 256) {
        s += (double)part_sum[i];
        m  = fmaxf(m, part_max[i]);
    }
    #pragma unroll
    for (int off = 32; off > 0; off >>= 1) {
        s += __shfl_down(s, off);
        m  = fmaxf(m, __shfl_down(m, off));
    }
    __shared__ double ds[4];
    __shared__ float  dm[4];
    if (lane == 0) { ds[wave] = s; dm[wave] = m; }
    __syncthreads();
    if (tid == 0) {
        const double S = ds[0] + ds[1] + ds[2] + ds[3];
        const float  M = fmaxf(fmaxf(dm[0], dm[1]), fmaxf(dm[2], dm[3]));
        *loss_out = (float)(S / (double)NELEM);
        *amax_out = M;
    }
}

extern "C" void kernel_launch(void* const* d_in, const int* in_sizes, int n_in,
                              void* d_out, int out_size, void* d_ws, size_t ws_size,
                              hipStream_t stream) {
    const float* x     = (const float*)d_in[0];
    const float* coeff = (const float*)d_in[1];
    const float* ref   = (const float*)d_in[2];

    float* outf = (float*)d_out;
    float* loss_out = outf;               // d_out[0]
    float* amax_out = outf + 1 + NELEM;   // d_out[N+1]

    float* part_sum = (float*)d_ws;
    float* part_max = part_sum + NBLK;

    stencil7_kernel<<<dim3(NBLK), dim3(256), 0, stream>>>(
        x, coeff, ref, outf, part_sum, part_max);
    finalize_kernel<<<dim3(1), dim3(256), 0, stream>>>(
        part_sum, part_max, loss_out, amax_out);
}